// Round 3
// 247.302 us; speedup vs baseline: 1.0564x; 1.0564x over previous
//
#include <hip/hip_runtime.h>
#include <stdint.h>

#define NB 8
#define CI 128
#define CO 256
#define KS 7
#define LL 16384
#define CK (CI * KS)   // 896

typedef _Float16 half8 __attribute__((ext_vector_type(8)));
typedef _Float16 half2v __attribute__((ext_vector_type(2)));
typedef float floatx4 __attribute__((ext_vector_type(4)));
typedef uint32_t uintx4 __attribute__((ext_vector_type(4)));

__device__ __forceinline__ void load16_to_lds(const void* g, void* l) {
    __builtin_amdgcn_global_load_lds(
        (const __attribute__((address_space(1))) void*)g,
        (__attribute__((address_space(3))) void*)l, 16, 0, 0);
}

// ---------- x (NB, CI, LL) f32 -> xT (NB, LL, CI) f16 ----------
__global__ __launch_bounds__(256) void convert_x(const float* __restrict__ x,
                                                 _Float16* __restrict__ xT) {
    __shared__ uint32_t tile[64][65];   // 16.6 KB
    const int n  = blockIdx.y;
    const int l0 = blockIdx.x * 64;
    const int t  = threadIdx.x;
    const float* xs = x + (size_t)n * CI * LL + l0;

    const int l4  = (t & 15) * 4;
    const int cpr = t >> 4;            // 0..15
    #pragma unroll
    for (int p = 0; p < 4; ++p) {
        const int cp = cpr + p * 16;   // c-pair 0..63
        const float4 a4 = *(const float4*)(xs + (size_t)(2 * cp) * LL + l4);
        const float4 b4 = *(const float4*)(xs + (size_t)(2 * cp + 1) * LL + l4);
        half2v h;
        h[0] = (_Float16)a4.x; h[1] = (_Float16)b4.x;
        tile[l4 + 0][cp] = __builtin_bit_cast(uint32_t, h);
        h[0] = (_Float16)a4.y; h[1] = (_Float16)b4.y;
        tile[l4 + 1][cp] = __builtin_bit_cast(uint32_t, h);
        h[0] = (_Float16)a4.z; h[1] = (_Float16)b4.z;
        tile[l4 + 2][cp] = __builtin_bit_cast(uint32_t, h);
        h[0] = (_Float16)a4.w; h[1] = (_Float16)b4.w;
        tile[l4 + 3][cp] = __builtin_bit_cast(uint32_t, h);
    }
    __syncthreads();

    const int lw  = t >> 4;            // 0..15
    const int cp0 = (t & 15) * 4;
    _Float16* xd = xT + (size_t)n * LL * CI + (size_t)l0 * CI;
    #pragma unroll
    for (int p = 0; p < 4; ++p) {
        const int l = lw + p * 16;
        uintx4 d;
        d[0] = tile[l][cp0 + 0];
        d[1] = tile[l][cp0 + 1];
        d[2] = tile[l][cp0 + 2];
        d[3] = tile[l][cp0 + 3];
        *(uintx4*)(xd + (size_t)l * CI + cp0 * 2) = d;
    }
}

// ---------- w (CO, CI, KS) f32 -> wT (CO, KS*CI) f16 ck-order, + 128-half zero row ----------
__global__ __launch_bounds__(256) void convert_w(const float* __restrict__ w,
                                                 _Float16* __restrict__ wT) {
    const int t = blockIdx.x * 256 + threadIdx.x;
    if (t >= CO * CK + 128) return;
    if (t >= CO * CK) { wT[t] = (_Float16)0.f; return; }
    const int o = t / CK;
    const int r = t - o * CK;
    const int k = r >> 7;
    const int c = r & 127;
    wT[t] = (_Float16)w[(size_t)o * CK + c * KS + k];
}

// ---------- MFMA GEMM: double-buffered LDS + XOR chunk swizzle + setprio ----------
// Per 128B LDS row (64 halfs = 8 chunks of 16B): physical chunk p of row r holds
// logical chunk p ^ (r&7).  Staging keeps the LDS dest LINEAR (global_load_lds
// writes base+lane*16) and pre-swizzles the GLOBAL source; ds_read applies the
// same involution.  Post-swizzle a wave64 ds_read_b128 hits each bank exactly
// 8x (the minimum) instead of 16 lanes on 4 banks.
__global__ __launch_bounds__(256) void iconv_mfma(
    const _Float16* __restrict__ xT,   // (NB, LL, CI)
    const int*      __restrict__ idx,  // (KS, LL), -1 = masked
    const _Float16* __restrict__ wT,   // (CO, CK)
    const float*    __restrict__ bias, // (CO)
    const _Float16* __restrict__ zrow, // 128 halfs of zeros
    float*          __restrict__ out)  // (NB, CO, LL)
{
    __shared__ _Float16 a_lds[2][128 * 64];   // 2 x 16 KB
    __shared__ _Float16 b_lds[2][128 * 64];   // 2 x 16 KB

    const int l0 = blockIdx.x * 128;
    const int o0 = blockIdx.y * 128;
    const int n  = blockIdx.z;
    const int t  = threadIdx.x;
    const int lane = t & 63;
    const int wv = t >> 6;
    const int wo = (wv >> 1) * 64;
    const int wl = (wv & 1) * 64;
    const int m16 = lane & 15;
    const int l4g = lane >> 4;         // 0..3
    const int swz = (m16 & 7);         // read-side row swizzle key

    floatx4 acc[4][4];
    #pragma unroll
    for (int i = 0; i < 4; ++i)
        #pragma unroll
        for (int j = 0; j < 4; ++j) acc[i][j] = (floatx4)0.f;

    // staging geometry: 128 rows x 128 B per operand; thread -> (row, chunk)
    const int srow = t >> 3;                       // 0..31 (+ i*32)
    const int part = t & 7;                        // physical chunk 0..7
    const int sp   = (part ^ (srow & 7)) * 8;      // swizzled SOURCE offset (halfs)
    const int dst  = srow * 64 + part * 8;         // LINEAR LDS dest (halfs); + i*2048

    // prefetch all idx into regs: no dependent loads inside the pipeline
    int iv[KS][4];
    #pragma unroll
    for (int k = 0; k < KS; ++k)
        #pragma unroll
        for (int i = 0; i < 4; ++i)
            iv[k][i] = idx[k * LL + l0 + i * 32 + srow];

    const _Float16* xbase = xT + (size_t)n * LL * CI;
    const _Float16* wbase = wT + (size_t)(o0 + srow) * CK;

    // ---- software pipeline: stage(it+1) issued before compute(it), one barrier/iter
    // it = k*2 + half : k = it>>1, c0 = (it&1)*64.  Fully unrolled -> all LDS
    // buffer selects and iv[k] indices are compile-time constants.
    {   // prologue: stage iteration 0 into buffer 0
        const int k = 0, c0 = 0;
        #pragma unroll
        for (int i = 0; i < 4; ++i) {
            const int ii = iv[k][i];
            const _Float16* bs = (ii >= 0)
                ? (xbase + (size_t)ii * CI + c0 + sp)
                : (zrow + c0 + sp);
            load16_to_lds(bs, &b_lds[0][i * 2048 + dst]);
            load16_to_lds(wbase + (size_t)i * 32 * CK + k * CI + c0 + sp,
                          &a_lds[0][i * 2048 + dst]);
        }
    }
    __syncthreads();

    #pragma unroll
    for (int it = 0; it < 2 * KS; ++it) {
        const int cur = it & 1;
        // -- issue next-tile staging first (overlaps with compute below)
        if (it < 2 * KS - 1) {
            const int nit = it + 1;
            const int nk  = nit >> 1;
            const int nc0 = (nit & 1) * 64;
            const int nb  = nit & 1;
            #pragma unroll
            for (int i = 0; i < 4; ++i) {
                const int ii = iv[nk][i];
                const _Float16* bs = (ii >= 0)
                    ? (xbase + (size_t)ii * CI + nc0 + sp)
                    : (zrow + nc0 + sp);
                load16_to_lds(bs, &b_lds[nb][i * 2048 + dst]);
                load16_to_lds(wbase + (size_t)i * 32 * CK + nk * CI + nc0 + sp,
                              &a_lds[nb][i * 2048 + dst]);
            }
        }

        // -- compute current tile (swizzled ds_read_b128, conflict-free)
        #pragma unroll
        for (int kk = 0; kk < 2; ++kk) {
            const int ch = ((kk * 4 + l4g) ^ swz) * 8;   // swizzled chunk (halfs)
            half8 af[4], bf[4];
            #pragma unroll
            for (int mf = 0; mf < 4; ++mf)
                af[mf] = *(const half8*)(&a_lds[cur][(wo + mf * 16 + m16) * 64 + ch]);
            #pragma unroll
            for (int nf = 0; nf < 4; ++nf)
                bf[nf] = *(const half8*)(&b_lds[cur][(wl + nf * 16 + m16) * 64 + ch]);
            __builtin_amdgcn_s_setprio(1);
            #pragma unroll
            for (int mf = 0; mf < 4; ++mf)
                #pragma unroll
                for (int nf = 0; nf < 4; ++nf)
                    acc[mf][nf] = __builtin_amdgcn_mfma_f32_16x16x32_f16(
                        af[mf], bf[nf], acc[mf][nf], 0, 0, 0);
            __builtin_amdgcn_s_setprio(0);
        }

        // barrier drains this iteration's stage loads (vmcnt) and LDS reads
        __syncthreads();
    }

    // epilogue: D[m][n]: m(row)=o=(lane>>4)*4+reg, n(col)=l=lane&15
    const int r4 = (lane >> 4) * 4;
    #pragma unroll
    for (int mf = 0; mf < 4; ++mf) {
        const int obase = o0 + wo + mf * 16 + r4;
        const floatx4 b4 = *(const floatx4*)(bias + obase);
        #pragma unroll
        for (int nf = 0; nf < 4; ++nf) {
            const int l = l0 + wl + nf * 16 + m16;
            float* op = out + ((size_t)n * CO + obase) * LL + l;
            #pragma unroll
            for (int r = 0; r < 4; ++r)
                op[(size_t)r * LL] = acc[mf][nf][r] + b4[r];
        }
    }
}

// ---------- fp32 fallback (only if workspace too small) ----------
__global__ __launch_bounds__(256) void iconv_fallback(
    const float* __restrict__ x, const int* __restrict__ idx,
    const float* __restrict__ w, const float* __restrict__ bias,
    float* __restrict__ out)
{
    __shared__ float col[CI][64];
    const int n  = blockIdx.y;
    const int l0 = blockIdx.x * 64;
    const int t  = threadIdx.x;
    const int ot = t & 63, lt = t >> 6;
    const int j = t >> 2, part = t & 3;
    float acc[4][16];
    #pragma unroll
    for (int oo = 0; oo < 4; ++oo) {
        const float bv = bias[ot * 4 + oo];
        #pragma unroll
        for (int ll = 0; ll < 16; ++ll) acc[oo][ll] = bv;
    }
    for (int k = 0; k < KS; ++k) {
        __syncthreads();
        const int i = idx[k * LL + l0 + j];
        const float* xr = x + (size_t)n * CI * LL;
        for (int q = 0; q < 32; ++q) {
            const int c = part * 32 + q;
            col[c][j] = (i >= 0) ? xr[(size_t)c * LL + i] : 0.f;
        }
        __syncthreads();
        for (int c = 0; c < CI; ++c) {
            const float* bv = &col[c][lt * 16];
            float wv[4];
            #pragma unroll
            for (int oo = 0; oo < 4; ++oo)
                wv[oo] = w[(size_t)(ot * 4 + oo) * CK + c * KS + k];
            #pragma unroll
            for (int oo = 0; oo < 4; ++oo)
                #pragma unroll
                for (int ll = 0; ll < 16; ++ll)
                    acc[oo][ll] += wv[oo] * bv[ll];
        }
    }
    #pragma unroll
    for (int oo = 0; oo < 4; ++oo) {
        float* orow = out + ((size_t)n * CO + (ot * 4 + oo)) * LL + l0 + lt * 16;
        #pragma unroll
        for (int q = 0; q < 16; ++q) orow[q] = acc[oo][q];
    }
}

extern "C" void kernel_launch(void* const* d_in, const int* in_sizes, int n_in,
                              void* d_out, int out_size, void* d_ws, size_t ws_size,
                              hipStream_t stream) {
    const float* x    = (const float*)d_in[0];
    const int*   idx  = (const int*)d_in[1];
    const float* w    = (const float*)d_in[2];
    const float* bias = (const float*)d_in[3];
    float* out = (float*)d_out;

    const size_t xt_bytes = (size_t)NB * LL * CI * sizeof(_Float16);     // 32 MiB
    const size_t wt_elems = (size_t)CO * CK + 128;                       // incl. zero row
    const size_t need = xt_bytes + wt_elems * sizeof(_Float16);

    if (ws_size >= need) {
        _Float16* xT = (_Float16*)d_ws;
        _Float16* wT = (_Float16*)((char*)d_ws + xt_bytes);
        const _Float16* zr = wT + (size_t)CO * CK;
        convert_x<<<dim3(LL / 64, NB), 256, 0, stream>>>(x, xT);
        convert_w<<<dim3(((int)wt_elems + 255) / 256), 256, 0, stream>>>(w, wT);
        iconv_mfma<<<dim3(LL / 128, CO / 128, NB), 256, 0, stream>>>(
            xT, idx, wT, bias, zr, out);
    } else {
        iconv_fallback<<<dim3(LL / 64, NB), 256, 0, stream>>>(x, idx, w, bias, out);
    }
}

// Round 4
// 241.659 us; speedup vs baseline: 1.0810x; 1.0234x over previous
//
#include <hip/hip_runtime.h>
#include <stdint.h>

#define NB 8
#define CI 128
#define CO 256
#define KS 7
#define LL 16384
#define CK (CI * KS)   // 896

typedef _Float16 half8 __attribute__((ext_vector_type(8)));
typedef _Float16 half2v __attribute__((ext_vector_type(2)));
typedef float floatx4 __attribute__((ext_vector_type(4)));
typedef uint32_t uintx4 __attribute__((ext_vector_type(4)));

__device__ __forceinline__ void load16_to_lds(const void* g, void* l) {
    __builtin_amdgcn_global_load_lds(
        (const __attribute__((address_space(1))) void*)g,
        (__attribute__((address_space(3))) void*)l, 16, 0, 0);
}

// ---------- x (NB, CI, LL) f32 -> xT (NB, LL, CI) f16 ----------
__global__ __launch_bounds__(256) void convert_x(const float* __restrict__ x,
                                                 _Float16* __restrict__ xT) {
    __shared__ uint32_t tile[64][65];   // 16.6 KB
    const int n  = blockIdx.y;
    const int l0 = blockIdx.x * 64;
    const int t  = threadIdx.x;
    const float* xs = x + (size_t)n * CI * LL + l0;

    const int l4  = (t & 15) * 4;
    const int cpr = t >> 4;            // 0..15
    #pragma unroll
    for (int p = 0; p < 4; ++p) {
        const int cp = cpr + p * 16;   // c-pair 0..63
        const float4 a4 = *(const float4*)(xs + (size_t)(2 * cp) * LL + l4);
        const float4 b4 = *(const float4*)(xs + (size_t)(2 * cp + 1) * LL + l4);
        half2v h;
        h[0] = (_Float16)a4.x; h[1] = (_Float16)b4.x;
        tile[l4 + 0][cp] = __builtin_bit_cast(uint32_t, h);
        h[0] = (_Float16)a4.y; h[1] = (_Float16)b4.y;
        tile[l4 + 1][cp] = __builtin_bit_cast(uint32_t, h);
        h[0] = (_Float16)a4.z; h[1] = (_Float16)b4.z;
        tile[l4 + 2][cp] = __builtin_bit_cast(uint32_t, h);
        h[0] = (_Float16)a4.w; h[1] = (_Float16)b4.w;
        tile[l4 + 3][cp] = __builtin_bit_cast(uint32_t, h);
    }
    __syncthreads();

    const int lw  = t >> 4;            // 0..15
    const int cp0 = (t & 15) * 4;
    _Float16* xd = xT + (size_t)n * LL * CI + (size_t)l0 * CI;
    #pragma unroll
    for (int p = 0; p < 4; ++p) {
        const int l = lw + p * 16;
        uintx4 d;
        d[0] = tile[l][cp0 + 0];
        d[1] = tile[l][cp0 + 1];
        d[2] = tile[l][cp0 + 2];
        d[3] = tile[l][cp0 + 3];
        *(uintx4*)(xd + (size_t)l * CI + cp0 * 2) = d;
    }
}

// ---------- w (CO, CI, KS) f32 -> wT (CO, KS*CI) f16 ck-order, + 128-half zero row ----------
__global__ __launch_bounds__(256) void convert_w(const float* __restrict__ w,
                                                 _Float16* __restrict__ wT) {
    const int t = blockIdx.x * 256 + threadIdx.x;
    if (t >= CO * CK + 128) return;
    if (t >= CO * CK) { wT[t] = (_Float16)0.f; return; }
    const int o = t / CK;
    const int r = t - o * CK;
    const int k = r >> 7;
    const int c = r & 127;
    wT[t] = (_Float16)w[(size_t)o * CK + c * KS + k];
}

// ---------- MFMA GEMM: dbuf LDS + XOR swizzle + COUNTED vmcnt pipeline ----------
// T3/T4 schedule (per proven 8-phase template): per iteration
//   issue stage(it+1) -> s_waitcnt vmcnt(8)  [stage(it) forced complete;
//   never drains the 8 in-flight stage(it+1) loads] -> s_barrier ->
//   sched_barrier(0) -> ds_read+MFMA -> lgkmcnt(0)+s_barrier (WAR, no vm drain).
// vmcnt(8) robustness: the 8 newest vmem ops are stage(it+1) (pinned above the
// wait by the "memory" clobber); anything older — incl. all of stage(it) and
// any compiler-interleaved loads — must complete.  Under-wait impossible.
__global__ __launch_bounds__(256) void iconv_mfma(
    const _Float16* __restrict__ xT,   // (NB, LL, CI)
    const int*      __restrict__ idx,  // (KS, LL), -1 = masked
    const _Float16* __restrict__ wT,   // (CO, CK)
    const float*    __restrict__ bias, // (CO)
    const _Float16* __restrict__ zrow, // 128 halfs of zeros
    float*          __restrict__ out)  // (NB, CO, LL)
{
    __shared__ _Float16 a_lds[2][128 * 64];   // 2 x 16 KB
    __shared__ _Float16 b_lds[2][128 * 64];   // 2 x 16 KB

    const int l0 = blockIdx.x * 128;
    const int o0 = blockIdx.y * 128;
    const int n  = blockIdx.z;
    const int t  = threadIdx.x;
    const int lane = t & 63;
    const int wv = t >> 6;
    const int wo = (wv >> 1) * 64;
    const int wl = (wv & 1) * 64;
    const int m16 = lane & 15;
    const int l4g = lane >> 4;         // 0..3
    const int swz = (m16 & 7);         // read-side row swizzle key

    floatx4 acc[4][4];
    #pragma unroll
    for (int i = 0; i < 4; ++i)
        #pragma unroll
        for (int j = 0; j < 4; ++j) acc[i][j] = (floatx4)0.f;

    // staging geometry: 128 rows x 128 B per operand; thread -> (row, chunk)
    const int srow = t >> 3;                       // 0..31 (+ i*32)
    const int part = t & 7;                        // physical chunk 0..7
    const int sp   = (part ^ (srow & 7)) * 8;      // swizzled SOURCE offset (halfs)
    const int dst  = srow * 64 + part * 8;         // LINEAR LDS dest (halfs); + i*2048

    // prefetch all idx into regs: no dependent loads inside the pipeline
    int iv[KS][4];
    #pragma unroll
    for (int k = 0; k < KS; ++k)
        #pragma unroll
        for (int i = 0; i < 4; ++i)
            iv[k][i] = idx[k * LL + l0 + i * 32 + srow];

    const _Float16* xbase = xT + (size_t)n * LL * CI;
    const _Float16* wbase = wT + (size_t)(o0 + srow) * CK;

    {   // prologue: stage iteration 0 into buffer 0
        const int k = 0, c0 = 0;
        #pragma unroll
        for (int i = 0; i < 4; ++i) {
            const int ii = iv[k][i];
            const _Float16* bs = (ii >= 0)
                ? (xbase + (size_t)ii * CI + c0 + sp)
                : (zrow + c0 + sp);
            load16_to_lds(bs, &b_lds[0][i * 2048 + dst]);
            load16_to_lds(wbase + (size_t)i * 32 * CK + k * CI + c0 + sp,
                          &a_lds[0][i * 2048 + dst]);
        }
    }

    #pragma unroll
    for (int it = 0; it < 2 * KS; ++it) {
        const int cur = it & 1;
        // -- issue next-tile staging (stays in flight ACROSS the barrier)
        if (it < 2 * KS - 1) {
            const int nit = it + 1;
            const int nk  = nit >> 1;
            const int nc0 = (nit & 1) * 64;
            const int nb  = nit & 1;
            #pragma unroll
            for (int i = 0; i < 4; ++i) {
                const int ii = iv[nk][i];
                const _Float16* bs = (ii >= 0)
                    ? (xbase + (size_t)ii * CI + nc0 + sp)
                    : (zrow + nc0 + sp);
                load16_to_lds(bs, &b_lds[nb][i * 2048 + dst]);
                load16_to_lds(wbase + (size_t)i * 32 * CK + nk * CI + nc0 + sp,
                              &a_lds[nb][i * 2048 + dst]);
            }
            asm volatile("s_waitcnt vmcnt(8)" ::: "memory");
        } else {
            asm volatile("s_waitcnt vmcnt(0)" ::: "memory");
        }
        __builtin_amdgcn_s_barrier();          // B1: buf[cur] filled block-wide
        __builtin_amdgcn_sched_barrier(0);     // pin ds_reads below the barrier

        // -- compute current tile (swizzled ds_read_b128, conflict-free)
        #pragma unroll
        for (int kk = 0; kk < 2; ++kk) {
            const int ch = ((kk * 4 + l4g) ^ swz) * 8;   // swizzled chunk (halfs)
            half8 af[4], bf[4];
            #pragma unroll
            for (int mf = 0; mf < 4; ++mf)
                af[mf] = *(const half8*)(&a_lds[cur][(wo + mf * 16 + m16) * 64 + ch]);
            #pragma unroll
            for (int nf = 0; nf < 4; ++nf)
                bf[nf] = *(const half8*)(&b_lds[cur][(wl + nf * 16 + m16) * 64 + ch]);
            __builtin_amdgcn_s_setprio(1);
            #pragma unroll
            for (int mf = 0; mf < 4; ++mf)
                #pragma unroll
                for (int nf = 0; nf < 4; ++nf)
                    acc[mf][nf] = __builtin_amdgcn_mfma_f32_16x16x32_f16(
                        af[mf], bf[nf], acc[mf][nf], 0, 0, 0);
            __builtin_amdgcn_s_setprio(0);
        }

        // B2: WAR protect for buf[cur] (rewritten by stage(it+2) next iter).
        // lgkmcnt(0) only — NO vmcnt drain; stage(it+1) stays in flight.
        if (it < 2 * KS - 2) {
            asm volatile("s_waitcnt lgkmcnt(0)" ::: "memory");
            __builtin_amdgcn_sched_barrier(0);
            __builtin_amdgcn_s_barrier();
            __builtin_amdgcn_sched_barrier(0); // pin next stage issue below
        }
    }

    // epilogue: D[m][n]: m(row)=o=(lane>>4)*4+reg, n(col)=l=lane&15
    const int r4 = (lane >> 4) * 4;
    #pragma unroll
    for (int mf = 0; mf < 4; ++mf) {
        const int obase = o0 + wo + mf * 16 + r4;
        const floatx4 b4 = *(const floatx4*)(bias + obase);
        #pragma unroll
        for (int nf = 0; nf < 4; ++nf) {
            const int l = l0 + wl + nf * 16 + m16;
            float* op = out + ((size_t)n * CO + obase) * LL + l;
            #pragma unroll
            for (int r = 0; r < 4; ++r)
                op[(size_t)r * LL] = acc[mf][nf][r] + b4[r];
        }
    }
}

// ---------- fp32 fallback (only if workspace too small) ----------
__global__ __launch_bounds__(256) void iconv_fallback(
    const float* __restrict__ x, const int* __restrict__ idx,
    const float* __restrict__ w, const float* __restrict__ bias,
    float* __restrict__ out)
{
    __shared__ float col[CI][64];
    const int n  = blockIdx.y;
    const int l0 = blockIdx.x * 64;
    const int t  = threadIdx.x;
    const int ot = t & 63, lt = t >> 6;
    const int j = t >> 2, part = t & 3;
    float acc[4][16];
    #pragma unroll
    for (int oo = 0; oo < 4; ++oo) {
        const float bv = bias[ot * 4 + oo];
        #pragma unroll
        for (int ll = 0; ll < 16; ++ll) acc[oo][ll] = bv;
    }
    for (int k = 0; k < KS; ++k) {
        __syncthreads();
        const int i = idx[k * LL + l0 + j];
        const float* xr = x + (size_t)n * CI * LL;
        for (int q = 0; q < 32; ++q) {
            const int c = part * 32 + q;
            col[c][j] = (i >= 0) ? xr[(size_t)c * LL + i] : 0.f;
        }
        __syncthreads();
        for (int c = 0; c < CI; ++c) {
            const float* bv = &col[c][lt * 16];
            float wv[4];
            #pragma unroll
            for (int oo = 0; oo < 4; ++oo)
                wv[oo] = w[(size_t)(ot * 4 + oo) * CK + c * KS + k];
            #pragma unroll
            for (int oo = 0; oo < 4; ++oo)
                #pragma unroll
                for (int ll = 0; ll < 16; ++ll)
                    acc[oo][ll] += wv[oo] * bv[ll];
        }
    }
    #pragma unroll
    for (int oo = 0; oo < 4; ++oo) {
        float* orow = out + ((size_t)n * CO + (ot * 4 + oo)) * LL + l0 + lt * 16;
        #pragma unroll
        for (int q = 0; q < 16; ++q) orow[q] = acc[oo][q];
    }
}

extern "C" void kernel_launch(void* const* d_in, const int* in_sizes, int n_in,
                              void* d_out, int out_size, void* d_ws, size_t ws_size,
                              hipStream_t stream) {
    const float* x    = (const float*)d_in[0];
    const int*   idx  = (const int*)d_in[1];
    const float* w    = (const float*)d_in[2];
    const float* bias = (const float*)d_in[3];
    float* out = (float*)d_out;

    const size_t xt_bytes = (size_t)NB * LL * CI * sizeof(_Float16);     // 32 MiB
    const size_t wt_elems = (size_t)CO * CK + 128;                       // incl. zero row
    const size_t need = xt_bytes + wt_elems * sizeof(_Float16);

    if (ws_size >= need) {
        _Float16* xT = (_Float16*)d_ws;
        _Float16* wT = (_Float16*)((char*)d_ws + xt_bytes);
        const _Float16* zr = wT + (size_t)CO * CK;
        convert_x<<<dim3(LL / 64, NB), 256, 0, stream>>>(x, xT);
        convert_w<<<dim3(((int)wt_elems + 255) / 256), 256, 0, stream>>>(w, wT);
        iconv_mfma<<<dim3(LL / 128, CO / 128, NB), 256, 0, stream>>>(
            xT, idx, wT, bias, zr, out);
    } else {
        iconv_fallback<<<dim3(LL / 64, NB), 256, 0, stream>>>(x, idx, w, bias, out);
    }
}